// Round 5
// baseline (301.736 us; speedup 1.0000x reference)
//
#include <hip/hip_runtime.h>
#include <hip/hip_bf16.h>
#include <cstddef>

#define NB 16
#define NQ 300
#define DM 256
#define LV_ 8400

typedef __attribute__((ext_vector_type(8))) short short8;
typedef __attribute__((ext_vector_type(4))) float f32x4;

static __device__ __forceinline__ unsigned short bf16_rne(float f) {
  unsigned int u = __builtin_bit_cast(unsigned int, f);
  u += 0x7FFFu + ((u >> 16) & 1u);
  return (unsigned short)(u >> 16);
}

static __device__ __forceinline__ unsigned int pack_bf2(float a, float b) {
  __hip_bfloat162 p = __float22bfloat162_rn(make_float2(a, b));
  unsigned int u;
  __builtin_memcpy(&u, &p, 4);
  return u;
}

// async global->LDS, 16 bytes per lane. LDS dest = wave-uniform base + lane*16.
static __device__ __forceinline__ void gload16(const void* g, void* l) {
  __builtin_amdgcn_global_load_lds(
      (const __attribute__((address_space(1))) unsigned int*)g,
      (__attribute__((address_space(3))) unsigned int*)l, 16, 0, 0);
}

// ---------------------------------------------------------------------------
// Kernel 0: weight prep.
//  z==0: Wv -> WthP, bf16, permuted into the exact LDS-staging-linear order
//        [y(col-half)][kb(k/32)][q(k8-chunk)][col(128)][8 bf16]
//        so vproj's B staging is a perfectly-coalesced linear copy.
//  z==1: Wout -> WoutT[n][k] bf16 (plain transpose, as before).
// grid (8,8,2), 256 threads.
// ---------------------------------------------------------------------------
__global__ __launch_bounds__(256) void prep_kernel(
    const float* __restrict__ Wv, const float* __restrict__ Wout,
    unsigned short* __restrict__ WthP, unsigned short* __restrict__ WoutT) {
  __shared__ float tle[32][33];
  const int k0 = blockIdx.x * 32, n0 = blockIdx.y * 32;
  const int xx = threadIdx.x & 31, y4 = (threadIdx.x >> 5) * 4;
  const float* src = blockIdx.z ? Wout : Wv;
  #pragma unroll
  for (int i = 0; i < 4; ++i)
    tle[y4 + i][xx] = src[(size_t)(k0 + y4 + i) * DM + n0 + xx];
  __syncthreads();
  if (blockIdx.z == 0) {
    // WthP[(((y*8 + kb)*4 + q)*128 + col)*8 + f] = bf16(Wv[kb*32+q*8+f][y*128+col])
    if (threadIdx.x < 128) {
      const int nl = threadIdx.x >> 2, q8 = threadIdx.x & 3;
      const int n = n0 + nl, yy = n >> 7, col = n & 127;
      uint4 o;
      o.x = pack_bf2(tle[q8 * 8 + 0][nl], tle[q8 * 8 + 1][nl]);
      o.y = pack_bf2(tle[q8 * 8 + 2][nl], tle[q8 * 8 + 3][nl]);
      o.z = pack_bf2(tle[q8 * 8 + 4][nl], tle[q8 * 8 + 5][nl]);
      o.w = pack_bf2(tle[q8 * 8 + 6][nl], tle[q8 * 8 + 7][nl]);
      const size_t idx = ((((size_t)yy * 8 + blockIdx.x) * 4 + q8) * 128 + col) * 8;
      *(uint4*)&WthP[idx] = o;
    }
  } else {
    #pragma unroll
    for (int i = 0; i < 4; ++i)
      WoutT[(size_t)(n0 + y4 + i) * DM + k0 + xx] = bf16_rne(tle[xx][y4 + i]);
  }
}

// ---------------------------------------------------------------------------
// Kernel 1: v = value @ Wv + bv, bf16 MFMA.
// v7: 64x128 tile (was 128x128) -> LDS 32 KB -> 5 blocks/CU (2.3x occupancy).
// Same proven structure: gload_lds staging, 2-buffer, ONE barrier per K-step,
// A fp32 source-XOR swizzle, pre-permuted B, swapped-operand MFMA epilogue,
// bijective XCD swizzle (4200 = 8*525; A-stripe pairs same-XCD).
// 4 waves as 2x2 (32 rows x 64 cols each), acc[2][4] of 16x16x32.
// ---------------------------------------------------------------------------
__global__ __launch_bounds__(256, 5) void vproj_mfma(
    const float* __restrict__ A, const unsigned short* __restrict__ WthP,
    const float* __restrict__ bias, unsigned short* __restrict__ V) {
  __shared__ float Af[2][4][64][8];           // 2 x 8 KB, [buf][q][row][8 fp32]
  __shared__ unsigned short Bf[2][4][128][8]; // 2 x 8 KB, [buf][q][col][8 bf16]
  const int tid = threadIdx.x;
  const int lane = tid & 63;
  const int wave = tid >> 6;
  const int l16 = lane & 15, q4 = lane >> 4;
  const int wr = (wave >> 1) * 32, wc = (wave & 1) * 64;

  // bijective XCD swizzle over 4200 blocks (4200 = 8*525). Work pairs
  // (xb,0),(xb,1) are consecutive w -> same XCD chunk -> A-stripe L2 reuse.
  const int b = blockIdx.x;
  const int w = (b & 7) * 525 + (b >> 3);
  const int xb = w >> 1, y = w & 1;
  const size_t row0 = (size_t)xb * 64;
  const int col0 = y * 128;

  const unsigned short* bsrc = WthP + (size_t)y * 8 * 4096;

  // A staging: 2 issues/thread. issue u = wave*2+c (0..7): q = u>>1,
  //   row = (u&1)*32 + (lane>>1), h = lane&1 (16B half).
  //   XOR swizzle: physical half h holds logical half h ^ ((row>>2)&1),
  //   so inverse-swizzled SOURCE k = q*8 + ((h ^ bit)<<2).
  //   LDS dest byte = u*1024 + lane*16 (linear).
  // B staging: 2 issues/thread, plain linear copy of 1 KB chunks (unchanged).
#define STAGE(bufi, kb_) do {                                                  \
    _Pragma("unroll")                                                          \
    for (int c_ = 0; c_ < 2; ++c_) {                                           \
      const int u_ = wave * 2 + c_;                                            \
      const int row_ = (u_ & 1) * 32 + (lane >> 1);                            \
      const int h_ = lane & 1;                                                 \
      const int k_ = (u_ >> 1) * 8 + ((h_ ^ ((row_ >> 2) & 1)) << 2);          \
      gload16(A + (row0 + row_) * DM + (kb_) * 32 + k_,                        \
              (char*)&Af[bufi][0][0][0] + u_ * 1024);                          \
    }                                                                          \
    _Pragma("unroll")                                                          \
    for (int c_ = 0; c_ < 2; ++c_) {                                           \
      const int u_ = wave * 2 + c_;                                            \
      gload16(bsrc + (size_t)(kb_) * 4096 + u_ * 512 + lane * 8,               \
              (char*)&Bf[bufi][0][0][0] + u_ * 1024);                          \
    }                                                                          \
  } while (0)

  f32x4 acc[2][4];
  #pragma unroll
  for (int i = 0; i < 2; ++i)
    #pragma unroll
    for (int j = 0; j < 4; ++j) acc[i][j] = (f32x4)0.f;

  const int swf = ((l16 >> 2) & 1) << 2;  // float offset of logical half 0

  int buf = 0;
  STAGE(0, 0);
  __syncthreads();

  for (int kb = 0; kb < 8; ++kb) {
    if (kb < 7) STAGE(buf ^ 1, kb + 1);

    short8 bfr[4];
    #pragma unroll
    for (int j = 0; j < 4; ++j)
      bfr[j] = *(const short8*)&Bf[buf][q4][wc + j * 16 + l16][0];

    #pragma unroll
    for (int i = 0; i < 2; ++i) {
      const float* rp = &Af[buf][q4][wr + i * 16 + l16][0];
      const float4 lo = *(const float4*)(rp + swf);
      const float4 hi = *(const float4*)(rp + (4 ^ swf));
      uint4 p;
      p.x = pack_bf2(lo.x, lo.y); p.y = pack_bf2(lo.z, lo.w);
      p.z = pack_bf2(hi.x, hi.y); p.w = pack_bf2(hi.z, hi.w);
      const short8 af = __builtin_bit_cast(short8, p);
      #pragma unroll
      for (int j = 0; j < 4; ++j)
        acc[i][j] = __builtin_amdgcn_mfma_f32_16x16x32_bf16(bfr[j], af, acc[i][j], 0, 0, 0);
    }
    __syncthreads();
    buf ^= 1;
  }
#undef STAGE

  // Swapped C/D layout: lane holds C[row = wr+i*16+l16][cols wc+j*16+q4*4+(0..3)]
  #pragma unroll
  for (int i = 0; i < 2; ++i) {
    const size_t row = row0 + wr + i * 16 + l16;
    #pragma unroll
    for (int j = 0; j < 4; ++j) {
      const int col = col0 + wc + j * 16 + q4 * 4;
      const float4 bc = *(const float4*)&bias[col];
      uint2 o;
      o.x = pack_bf2(acc[i][j][0] + bc.x, acc[i][j][1] + bc.y);
      o.y = pack_bf2(acc[i][j][2] + bc.z, acc[i][j][3] + bc.w);
      *(uint2*)&V[row * DM + col] = o;
    }
  }
}

// ---------------------------------------------------------------------------
// Kernel 2: fused query projections (offsets N=192 + logits N=96), fp32.
// 32x32 tile, BK=32, 256 threads, 2x2 microtile, register-prefetched.
// grid (150, 9): by<6 -> Woff tile, else -> Wattn tile.
// ---------------------------------------------------------------------------
__global__ __launch_bounds__(256) void gemm_qp(
    const float* __restrict__ q,
    const float* __restrict__ Woff, const float* __restrict__ boff,
    const float* __restrict__ Wattn, const float* __restrict__ battn,
    float* __restrict__ offb, float* __restrict__ logitb) {
  const int by = blockIdx.y;
  const float* W; const float* bias; float* C; int N, c0;
  if (by < 6) { W = Woff;  bias = boff;  C = offb;   N = 192; c0 = by * 32; }
  else        { W = Wattn; bias = battn; C = logitb; N = 96;  c0 = (by - 6) * 32; }
  const int m0 = blockIdx.x * 32;

  __shared__ float As[32][33];   // As[k][m]
  __shared__ float Bs[32][33];   // Bs[k][n]
  const int tid = threadIdx.x;
  const int ar = tid >> 3, ak = (tid & 7) * 4;
  const int kr = tid >> 3, bc = (tid & 7) * 4;
  const int tx = tid & 15, ty = tid >> 4;

  const float* apt = q + (size_t)(m0 + ar) * DM + ak;
  float4 av = *(const float4*)apt;
  float4 wv = *(const float4*)(W + (size_t)kr * N + c0 + bc);

  float acc[2][2] = {{0.f, 0.f}, {0.f, 0.f}};
  for (int kk = 0; kk < DM; kk += 32) {
    __syncthreads();
    As[ak + 0][ar] = av.x;
    As[ak + 1][ar] = av.y;
    As[ak + 2][ar] = av.z;
    As[ak + 3][ar] = av.w;
    *(float4*)&Bs[kr][bc] = wv;
    __syncthreads();
    if (kk + 32 < DM) {
      av = *(const float4*)(apt + kk + 32);
      wv = *(const float4*)(W + (size_t)(kk + 32 + kr) * N + c0 + bc);
    }
    #pragma unroll
    for (int k = 0; k < 32; ++k) {
      const float2 a2 = *(const float2*)&As[k][ty * 2];
      const float2 b2 = *(const float2*)&Bs[k][tx * 2];
      acc[0][0] = fmaf(a2.x, b2.x, acc[0][0]);
      acc[0][1] = fmaf(a2.x, b2.y, acc[0][1]);
      acc[1][0] = fmaf(a2.y, b2.x, acc[1][0]);
      acc[1][1] = fmaf(a2.y, b2.y, acc[1][1]);
    }
  }
  const float b0 = bias[c0 + tx * 2], b1 = bias[c0 + tx * 2 + 1];
  #pragma unroll
  for (int i = 0; i < 2; ++i) {
    float2 o; o.x = acc[i][0] + b0; o.y = acc[i][1] + b1;
    *(float2*)&C[(size_t)(m0 + ty * 2 + i) * N + c0 + tx * 2] = o;
  }
}

// ---------------------------------------------------------------------------
// Kernel 3: softmax + bilinear deformable sampling. 2 queries per block,
// XCD-locality swizzle (each XCD serves 2 batches -> 8.6 MB L2 working set).
// idx/wt fused into int2 LDS pairs (ds_read_b64, half the LDS ops in the
// gather loop). Writes mid as bf16.
// ---------------------------------------------------------------------------
__global__ __launch_bounds__(256) void sample_kernel(
    const float* __restrict__ refp, const unsigned short* __restrict__ v,
    const float* __restrict__ off, const float* __restrict__ logits,
    unsigned short* __restrict__ mid) {
  // swizzle: XCD = blockIdx%8 (round-robin); give each XCD batches {c, c+8}
  const int x = blockIdx.x;
  const int c8 = x & 7, kb = x >> 3;          // kb in [0,300)
  const int b = c8 + (kb >= 150 ? 8 : 0);
  const int qp = (kb >= 150 ? kb - 150 : kb);
  const int bq0 = b * NQ + qp * 2;
  const int t = threadIdx.x;
  __shared__ float off_sh[2][192];
  __shared__ float aw_sh[2][96];
  __shared__ int2  iw_sh[2][96][4];   // {index, weight-bits}
  __shared__ float ref_sh[2][2];

  {
    const float* osrc = off + (size_t)bq0 * 192;
    float* odst = &off_sh[0][0];
    odst[t] = osrc[t];
    if (t < 128) odst[256 + t] = osrc[256 + t];
    const float* lsrc = logits + (size_t)bq0 * 96;
    if (t < 192) (&aw_sh[0][0])[t] = lsrc[t];
    if (t < 4) ref_sh[t >> 1][t & 1] = refp[(bq0 + (t >> 1)) * 4 + (t & 1)];
  }
  __syncthreads();

  if (t < 16) {
    const int q = t >> 3, h = t & 7;
    float* aw = &aw_sh[q][h * 12];
    float m = -1e30f;
    #pragma unroll
    for (int i = 0; i < 12; ++i) m = fmaxf(m, aw[i]);
    float e[12], s = 0.f;
    #pragma unroll
    for (int i = 0; i < 12; ++i) { e[i] = __expf(aw[i] - m); s += e[i]; }
    const float inv = 1.f / s;
    #pragma unroll
    for (int i = 0; i < 12; ++i) aw[i] = e[i] * inv;
  }
  __syncthreads();

  if (t < 192) {
    const int q = t / 96, r = t - q * 96;
    const int h = r / 12, lp = r - h * 12;
    const int l = lp >> 2, p = lp & 3;
    const int LH[3] = {80, 40, 20};
    const int LS[3] = {0, 6400, 8000};
    const int hh = LH[l], ww = LH[l], st = LS[l];
    const int oi = ((h * 3 + l) * 4 + p) * 2;
    const float aw = aw_sh[q][h * 12 + lp];
    const float sx = fminf(fmaxf(ref_sh[q][0] + off_sh[q][oi], 0.f), 1.f);
    const float sy = fminf(fmaxf(ref_sh[q][1] + off_sh[q][oi + 1], 0.f), 1.f);
    const float px = sx * (float)ww - 0.5f;
    const float py = sy * (float)hh - 0.5f;
    const float x0f = floorf(px), y0f = floorf(py);
    const float fx = px - x0f, fy = py - y0f;
    const int x0 = (int)x0f, y0 = (int)y0f;
    const int x1 = x0 + 1, y1 = y0 + 1;
    const bool vx0 = (x0 >= 0) & (x0 < ww), vx1 = (x1 >= 0) & (x1 < ww);
    const bool vy0 = (y0 >= 0) & (y0 < hh), vy1 = (y1 >= 0) & (y1 < hh);
    const int x0c = min(max(x0, 0), ww - 1), x1c = min(max(x1, 0), ww - 1);
    const int y0c = min(max(y0, 0), hh - 1), y1c = min(max(y1, 0), hh - 1);
    const float w0 = aw * (1.f - fx) * (1.f - fy) * ((vx0 & vy0) ? 1.f : 0.f);
    const float w1 = aw * fx * (1.f - fy) * ((vx1 & vy0) ? 1.f : 0.f);
    const float w2 = aw * (1.f - fx) * fy * ((vx0 & vy1) ? 1.f : 0.f);
    const float w3 = aw * fx * fy * ((vx1 & vy1) ? 1.f : 0.f);
    iw_sh[q][r][0] = make_int2(st + y0c * ww + x0c, __float_as_int(w0));
    iw_sh[q][r][1] = make_int2(st + y0c * ww + x1c, __float_as_int(w1));
    iw_sh[q][r][2] = make_int2(st + y1c * ww + x0c, __float_as_int(w2));
    iw_sh[q][r][3] = make_int2(st + y1c * ww + x1c, __float_as_int(w3));
  }
  __syncthreads();

  // gather: q = t>>7, head = (t>>4)&7, dim-pair = t&15
  const int q = t >> 7, h = (t >> 4) & 7, dp = t & 15;
  const unsigned short* vb = v + (size_t)b * LV_ * DM + h * 32 + dp * 2;
  float ax = 0.f, ay = 0.f;
  #pragma unroll
  for (int r = 0; r < 12; ++r) {
    const int rr = h * 12 + r;
    #pragma unroll
    for (int cc = 0; cc < 4; ++cc) {
      const int2 iw = iw_sh[q][rr][cc];
      const float w = __int_as_float(iw.y);
      const unsigned int u = *(const unsigned int*)(vb + (size_t)iw.x * DM);
      ax = fmaf(w, __builtin_bit_cast(float, u << 16), ax);
      ay = fmaf(w, __builtin_bit_cast(float, u & 0xFFFF0000u), ay);
    }
  }
  unsigned short* mp = mid + (size_t)(bq0 + q) * DM + h * 32 + dp * 2;
  *(unsigned int*)mp = pack_bf2(ax, ay);
}

// ---------------------------------------------------------------------------
// Kernel 4: out = mid @ Wout + bout, bf16 MFMA, 64x64 tile, BK=32,
// register-prefetch pipelined, SWAPPED-OPERAND MFMA -> float4 C-stores.
// grid (75, 4).
// ---------------------------------------------------------------------------
__global__ __launch_bounds__(256) void outp_mfma(
    const unsigned short* __restrict__ midb, const unsigned short* __restrict__ WoutT,
    const float* __restrict__ bias, float* __restrict__ out) {
  __shared__ short Ah[4][64][8];   // 4 KB
  __shared__ short Bh[4][64][8];   // 4 KB
  const int tid = threadIdx.x;
  const int lane = tid & 63;
  const int wave = tid >> 6;
  const int l16 = lane & 15, q4 = lane >> 4;
  const int wc = wave * 16;
  const int m0 = blockIdx.x * 64, col0 = blockIdx.y * 64;

  const int r = tid >> 2, ch = tid & 3;   // staging: row, k-chunk
  const unsigned short* apt = midb + (size_t)(m0 + r) * DM + ch * 8;
  const unsigned short* wpt = WoutT + (size_t)(col0 + r) * DM + ch * 8;
  uint4 am = *(const uint4*)apt;
  uint4 wm = *(const uint4*)wpt;

  f32x4 acc[4];
  #pragma unroll
  for (int i = 0; i < 4; ++i) acc[i] = (f32x4)0.f;

  for (int kk = 0; kk < DM; kk += 32) {
    __syncthreads();
    *(uint4*)&Ah[ch][r][0] = am;
    *(uint4*)&Bh[ch][r][0] = wm;
    __syncthreads();
    if (kk + 32 < DM) {
      am = *(const uint4*)(apt + kk + 32);
      wm = *(const uint4*)(wpt + kk + 32);
    }
    const short8 bfrag = *(const short8*)&Bh[q4][wc + l16][0];
    #pragma unroll
    for (int i = 0; i < 4; ++i) {
      const short8 af = *(const short8*)&Ah[q4][i * 16 + l16][0];
      acc[i] = __builtin_amdgcn_mfma_f32_16x16x32_bf16(bfrag, af, acc[i], 0, 0, 0);
    }
  }

  // Swapped C/D layout: lane holds C[row = m0+i*16+l16][cols col0+wc+q4*4+(0..3)]
  const int col = col0 + wc + q4 * 4;
  const float4 bc = *(const float4*)&bias[col];
  #pragma unroll
  for (int i = 0; i < 4; ++i) {
    float4 o;
    o.x = acc[i][0] + bc.x;
    o.y = acc[i][1] + bc.y;
    o.z = acc[i][2] + bc.z;
    o.w = acc[i][3] + bc.w;
    *(float4*)&out[(size_t)(m0 + i * 16 + l16) * DM + col] = o;
  }
}

extern "C" void kernel_launch(void* const* d_in, const int* in_sizes, int n_in,
                              void* d_out, int out_size, void* d_ws, size_t ws_size,
                              hipStream_t stream) {
  (void)in_sizes; (void)n_in; (void)out_size; (void)ws_size;
  const float* query = (const float*)d_in[0];
  const float* refp  = (const float*)d_in[1];
  const float* value = (const float*)d_in[2];
  const float* Wv    = (const float*)d_in[3];
  const float* bv    = (const float*)d_in[4];
  const float* Woff  = (const float*)d_in[5];
  const float* boff  = (const float*)d_in[6];
  const float* Wattn = (const float*)d_in[7];
  const float* battn = (const float*)d_in[8];
  const float* Wout  = (const float*)d_in[9];
  const float* bout  = (const float*)d_in[10];
  float* out = (float*)d_out;

  char* ws = (char*)d_ws;
  unsigned short* v_bf  = (unsigned short*)ws;              // 68,812,800 B
  unsigned short* WthP  = (unsigned short*)(ws + 68812800); // 131,072 B
  unsigned short* WoutT = (unsigned short*)(ws + 68943872); // 131,072 B
  float* offb   = (float*)(ws + 69074944);                  // 3,686,400 B
  float* logitb = (float*)(ws + 72761344);                  // 1,843,200 B
  unsigned short* midb = (unsigned short*)(ws + 74604544);  // 2,457,600 B

  prep_kernel<<<dim3(8, 8, 2), 256, 0, stream>>>(Wv, Wout, WthP, WoutT);
  gemm_qp<<<dim3(150, 9), 256, 0, stream>>>(query, Woff, boff, Wattn, battn, offb, logitb);
  vproj_mfma<<<4200, 256, 0, stream>>>(value, WthP, bv, v_bf);
  sample_kernel<<<2400, 256, 0, stream>>>(refp, v_bf, offb, logitb, midb);
  outp_mfma<<<dim3(75, 4), 256, 0, stream>>>(midb, WoutT, bout, out);
}

// Round 6
// 292.168 us; speedup vs baseline: 1.0327x; 1.0327x over previous
//
#include <hip/hip_runtime.h>
#include <hip/hip_bf16.h>
#include <cstddef>

#define NB 16
#define NQ 300
#define DM 256
#define LV_ 8400

typedef __attribute__((ext_vector_type(8))) short short8;
typedef __attribute__((ext_vector_type(4))) float f32x4;

static __device__ __forceinline__ unsigned short bf16_rne(float f) {
  unsigned int u = __builtin_bit_cast(unsigned int, f);
  u += 0x7FFFu + ((u >> 16) & 1u);
  return (unsigned short)(u >> 16);
}

static __device__ __forceinline__ unsigned int pack_bf2(float a, float b) {
  __hip_bfloat162 p = __float22bfloat162_rn(make_float2(a, b));
  unsigned int u;
  __builtin_memcpy(&u, &p, 4);
  return u;
}

// async global->LDS, 16 bytes per lane. LDS dest = wave-uniform base + lane*16.
static __device__ __forceinline__ void gload16(const void* g, void* l) {
  __builtin_amdgcn_global_load_lds(
      (const __attribute__((address_space(1))) unsigned int*)g,
      (__attribute__((address_space(3))) unsigned int*)l, 16, 0, 0);
}

// ---------------------------------------------------------------------------
// Kernel 0: weight prep.
//  z==0: Wv -> WthP, bf16, permuted into the exact LDS-staging-linear order
//        [y(col-half)][kb(k/32)][q(k8-chunk)][col(128)][8 bf16]
//        so vproj's B staging is a perfectly-coalesced linear copy.
//  z==1: Wout -> WoutT[n][k] bf16 (plain transpose, as before).
// grid (8,8,2), 256 threads.
// ---------------------------------------------------------------------------
__global__ __launch_bounds__(256) void prep_kernel(
    const float* __restrict__ Wv, const float* __restrict__ Wout,
    unsigned short* __restrict__ WthP, unsigned short* __restrict__ WoutT) {
  __shared__ float tle[32][33];
  const int k0 = blockIdx.x * 32, n0 = blockIdx.y * 32;
  const int xx = threadIdx.x & 31, y4 = (threadIdx.x >> 5) * 4;
  const float* src = blockIdx.z ? Wout : Wv;
  #pragma unroll
  for (int i = 0; i < 4; ++i)
    tle[y4 + i][xx] = src[(size_t)(k0 + y4 + i) * DM + n0 + xx];
  __syncthreads();
  if (blockIdx.z == 0) {
    // WthP[(((y*8 + kb)*4 + q)*128 + col)*8 + f] = bf16(Wv[kb*32+q*8+f][y*128+col])
    if (threadIdx.x < 128) {
      const int nl = threadIdx.x >> 2, q8 = threadIdx.x & 3;
      const int n = n0 + nl, yy = n >> 7, col = n & 127;
      uint4 o;
      o.x = pack_bf2(tle[q8 * 8 + 0][nl], tle[q8 * 8 + 1][nl]);
      o.y = pack_bf2(tle[q8 * 8 + 2][nl], tle[q8 * 8 + 3][nl]);
      o.z = pack_bf2(tle[q8 * 8 + 4][nl], tle[q8 * 8 + 5][nl]);
      o.w = pack_bf2(tle[q8 * 8 + 6][nl], tle[q8 * 8 + 7][nl]);
      const size_t idx = ((((size_t)yy * 8 + blockIdx.x) * 4 + q8) * 128 + col) * 8;
      *(uint4*)&WthP[idx] = o;
    }
  } else {
    #pragma unroll
    for (int i = 0; i < 4; ++i)
      WoutT[(size_t)(n0 + y4 + i) * DM + k0 + xx] = bf16_rne(tle[xx][y4 + i]);
  }
}

// ---------------------------------------------------------------------------
// Kernel 1: v = value @ Wv + bv, bf16 MFMA.
// M=134400, N=K=256. 128x128 tile, BK=32, 4 waves 2x2, 4x4 of 16x16x32.
// Round-1 v3 EXACT (best measured <=83.7): global_load_lds staging (A fp32
// w/ source-XOR swizzle, B bf16 linear), double-buffered LDS, ONE barrier
// per K-step, chunked-bijective XCD swizzle, UNSWAPPED mfma + row-contiguous
// C-stores (32B/quad coalescing).
// ---------------------------------------------------------------------------
__global__ __launch_bounds__(256, 3) void vproj_mfma(
    const float* __restrict__ A, const unsigned short* __restrict__ WthP,
    const float* __restrict__ bias, unsigned short* __restrict__ V) {
  __shared__ float Af[2][4][128][8];          // 2 x 16 KB, [buf][q][row][8 fp32]
  __shared__ unsigned short Bf[2][4][128][8]; // 2 x  8 KB, [buf][q][col][8 bf16]
  const int tid = threadIdx.x;
  const int lane = tid & 63;
  const int wave = tid >> 6;
  const int l16 = lane & 15, q4 = lane >> 4;
  const int wr = (wave >> 1) * 64, wc = (wave & 1) * 64;

  // bijective chunked XCD swizzle over 2100 blocks (2100 = 8*262 + 4):
  // work pairs (x,0),(x,1) share the same A stripe -> same-XCD L2 reuse.
  const int b = blockIdx.x;
  const int xcd = b & 7, cidx = b >> 3;
  const int w = (xcd < 4 ? xcd * 263 : 4 * 263 + (xcd - 4) * 262) + cidx;
  const int xb = w >> 1, y = w & 1;
  const size_t row0 = (size_t)xb * 128;
  const int col0 = y * 128;

  const unsigned short* bsrc = WthP + (size_t)y * 8 * 4096;

  // A staging: 4 issues/thread. issue u = wave*4+c: q=wave, rowblk=c.
  //   lane: row = c*32 + (lane>>1), h = lane&1.
  //   XOR swizzle: physical 16B-half h holds logical half h ^ ((row>>2)&1),
  //   so the inverse-swizzled SOURCE k = q*8 + ((h ^ bit)<<2).
  // B staging: 2 issues/thread, plain linear copy of 1 KB chunks.
#define STAGE(bufi, kb_) do {                                                  \
    _Pragma("unroll")                                                          \
    for (int c_ = 0; c_ < 4; ++c_) {                                           \
      const int u_ = wave * 4 + c_;                                            \
      const int row_ = c_ * 32 + (lane >> 1);                                  \
      const int h_ = lane & 1;                                                 \
      const int k_ = wave * 8 + ((h_ ^ ((row_ >> 2) & 1)) << 2);               \
      gload16(A + (row0 + row_) * DM + (kb_) * 32 + k_,                        \
              (char*)&Af[bufi][0][0][0] + u_ * 1024);                          \
    }                                                                          \
    _Pragma("unroll")                                                          \
    for (int c_ = 0; c_ < 2; ++c_) {                                           \
      const int u_ = wave * 2 + c_;                                            \
      gload16(bsrc + (size_t)(kb_) * 4096 + u_ * 512 + lane * 8,               \
              (char*)&Bf[bufi][0][0][0] + u_ * 1024);                          \
    }                                                                          \
  } while (0)

  f32x4 acc[4][4];
  #pragma unroll
  for (int i = 0; i < 4; ++i)
    #pragma unroll
    for (int j = 0; j < 4; ++j) acc[i][j] = (f32x4)0.f;

  const int swf = ((l16 >> 2) & 1) << 2;  // float offset of logical half 0

  int buf = 0;
  STAGE(0, 0);
  __syncthreads();

  for (int kb = 0; kb < 8; ++kb) {
    if (kb < 7) STAGE(buf ^ 1, kb + 1);

    short8 bfr[4];
    #pragma unroll
    for (int j = 0; j < 4; ++j)
      bfr[j] = *(const short8*)&Bf[buf][q4][wc + j * 16 + l16][0];

    #pragma unroll
    for (int i = 0; i < 4; ++i) {
      const float* rp = &Af[buf][q4][wr + i * 16 + l16][0];
      const float4 lo = *(const float4*)(rp + swf);
      const float4 hi = *(const float4*)(rp + (4 ^ swf));
      uint4 p;
      p.x = pack_bf2(lo.x, lo.y); p.y = pack_bf2(lo.z, lo.w);
      p.z = pack_bf2(hi.x, hi.y); p.w = pack_bf2(hi.z, hi.w);
      const short8 af = __builtin_bit_cast(short8, p);
      #pragma unroll
      for (int j = 0; j < 4; ++j)
        acc[i][j] = __builtin_amdgcn_mfma_f32_16x16x32_bf16(af, bfr[j], acc[i][j], 0, 0, 0);
    }
    __syncthreads();
    buf ^= 1;
  }
#undef STAGE

  // C/D layout: col = lane&15, row = (lane>>4)*4 + r
  #pragma unroll
  for (int i = 0; i < 4; ++i)
    #pragma unroll
    for (int j = 0; j < 4; ++j) {
      const int col = col0 + wc + j * 16 + l16;
      const float bcol = bias[col];
      #pragma unroll
      for (int r = 0; r < 4; ++r) {
        const size_t row = row0 + wr + i * 16 + q4 * 4 + r;
        V[row * DM + col] = bf16_rne(acc[i][j][r] + bcol);
      }
    }
}

// ---------------------------------------------------------------------------
// Kernel 2: fused query projections (offsets N=192 + logits N=96), fp32.
// 32x32 tile, BK=32, 256 threads, 2x2 microtile, register-prefetched.
// grid (150, 9): by<6 -> Woff tile, else -> Wattn tile.
// ---------------------------------------------------------------------------
__global__ __launch_bounds__(256) void gemm_qp(
    const float* __restrict__ q,
    const float* __restrict__ Woff, const float* __restrict__ boff,
    const float* __restrict__ Wattn, const float* __restrict__ battn,
    float* __restrict__ offb, float* __restrict__ logitb) {
  const int by = blockIdx.y;
  const float* W; const float* bias; float* C; int N, c0;
  if (by < 6) { W = Woff;  bias = boff;  C = offb;   N = 192; c0 = by * 32; }
  else        { W = Wattn; bias = battn; C = logitb; N = 96;  c0 = (by - 6) * 32; }
  const int m0 = blockIdx.x * 32;

  __shared__ float As[32][33];   // As[k][m]
  __shared__ float Bs[32][33];   // Bs[k][n]
  const int tid = threadIdx.x;
  const int ar = tid >> 3, ak = (tid & 7) * 4;
  const int kr = tid >> 3, bc = (tid & 7) * 4;
  const int tx = tid & 15, ty = tid >> 4;

  const float* apt = q + (size_t)(m0 + ar) * DM + ak;
  float4 av = *(const float4*)apt;
  float4 wv = *(const float4*)(W + (size_t)kr * N + c0 + bc);

  float acc[2][2] = {{0.f, 0.f}, {0.f, 0.f}};
  for (int kk = 0; kk < DM; kk += 32) {
    __syncthreads();
    As[ak + 0][ar] = av.x;
    As[ak + 1][ar] = av.y;
    As[ak + 2][ar] = av.z;
    As[ak + 3][ar] = av.w;
    *(float4*)&Bs[kr][bc] = wv;
    __syncthreads();
    if (kk + 32 < DM) {
      av = *(const float4*)(apt + kk + 32);
      wv = *(const float4*)(W + (size_t)(kk + 32 + kr) * N + c0 + bc);
    }
    #pragma unroll
    for (int k = 0; k < 32; ++k) {
      const float2 a2 = *(const float2*)&As[k][ty * 2];
      const float2 b2 = *(const float2*)&Bs[k][tx * 2];
      acc[0][0] = fmaf(a2.x, b2.x, acc[0][0]);
      acc[0][1] = fmaf(a2.x, b2.y, acc[0][1]);
      acc[1][0] = fmaf(a2.y, b2.x, acc[1][0]);
      acc[1][1] = fmaf(a2.y, b2.y, acc[1][1]);
    }
  }
  const float b0 = bias[c0 + tx * 2], b1 = bias[c0 + tx * 2 + 1];
  #pragma unroll
  for (int i = 0; i < 2; ++i) {
    float2 o; o.x = acc[i][0] + b0; o.y = acc[i][1] + b1;
    *(float2*)&C[(size_t)(m0 + ty * 2 + i) * N + c0 + tx * 2] = o;
  }
}

// ---------------------------------------------------------------------------
// Kernel 3: softmax + bilinear deformable sampling. v2: 4 queries per block,
// 512 threads, grid 1200 (halves per-query softmax/index/barrier overhead).
// XCD-locality swizzle (each XCD serves 2 batches -> 8.6 MB L2 working set).
// idx/wt fused into int2 LDS pairs. Writes mid as bf16.
// ---------------------------------------------------------------------------
__global__ __launch_bounds__(512) void sample_kernel(
    const float* __restrict__ refp, const unsigned short* __restrict__ v,
    const float* __restrict__ off, const float* __restrict__ logits,
    unsigned short* __restrict__ mid) {
  // swizzle: XCD = blockIdx%8 (round-robin); give each XCD batches {c, c+8}
  const int x = blockIdx.x;
  const int c8 = x & 7, kb = x >> 3;          // kb in [0,150)
  const int b = c8 + (kb >= 75 ? 8 : 0);
  const int qp = (kb >= 75 ? kb - 75 : kb);
  const int bq0 = b * NQ + qp * 4;
  const int t = threadIdx.x;
  __shared__ float off_sh[4][192];
  __shared__ float aw_sh[4][96];
  __shared__ int2  iw_sh[4][96][4];   // {index, weight-bits}
  __shared__ float ref_sh[4][2];

  {
    const float* osrc = off + (size_t)bq0 * 192;
    float* odst = &off_sh[0][0];
    odst[t] = osrc[t];
    if (t < 256) odst[512 + t] = osrc[512 + t];
    const float* lsrc = logits + (size_t)bq0 * 96;
    if (t < 384) (&aw_sh[0][0])[t] = lsrc[t];
    if (t < 8) ref_sh[t >> 1][t & 1] = refp[(bq0 + (t >> 1)) * 4 + (t & 1)];
  }
  __syncthreads();

  if (t < 32) {
    const int q = t >> 3, h = t & 7;
    float* aw = &aw_sh[q][h * 12];
    float m = -1e30f;
    #pragma unroll
    for (int i = 0; i < 12; ++i) m = fmaxf(m, aw[i]);
    float e[12], s = 0.f;
    #pragma unroll
    for (int i = 0; i < 12; ++i) { e[i] = __expf(aw[i] - m); s += e[i]; }
    const float inv = 1.f / s;
    #pragma unroll
    for (int i = 0; i < 12; ++i) aw[i] = e[i] * inv;
  }
  __syncthreads();

  if (t < 384) {
    const int q = t / 96, r = t - q * 96;
    const int h = r / 12, lp = r - h * 12;
    const int l = lp >> 2, p = lp & 3;
    const int LH[3] = {80, 40, 20};
    const int LS[3] = {0, 6400, 8000};
    const int hh = LH[l], ww = LH[l], st = LS[l];
    const int oi = ((h * 3 + l) * 4 + p) * 2;
    const float aw = aw_sh[q][h * 12 + lp];
    const float sx = fminf(fmaxf(ref_sh[q][0] + off_sh[q][oi], 0.f), 1.f);
    const float sy = fminf(fmaxf(ref_sh[q][1] + off_sh[q][oi + 1], 0.f), 1.f);
    const float px = sx * (float)ww - 0.5f;
    const float py = sy * (float)hh - 0.5f;
    const float x0f = floorf(px), y0f = floorf(py);
    const float fx = px - x0f, fy = py - y0f;
    const int x0 = (int)x0f, y0 = (int)y0f;
    const int x1 = x0 + 1, y1 = y0 + 1;
    const bool vx0 = (x0 >= 0) & (x0 < ww), vx1 = (x1 >= 0) & (x1 < ww);
    const bool vy0 = (y0 >= 0) & (y0 < hh), vy1 = (y1 >= 0) & (y1 < hh);
    const int x0c = min(max(x0, 0), ww - 1), x1c = min(max(x1, 0), ww - 1);
    const int y0c = min(max(y0, 0), hh - 1), y1c = min(max(y1, 0), hh - 1);
    const float w0 = aw * (1.f - fx) * (1.f - fy) * ((vx0 & vy0) ? 1.f : 0.f);
    const float w1 = aw * fx * (1.f - fy) * ((vx1 & vy0) ? 1.f : 0.f);
    const float w2 = aw * (1.f - fx) * fy * ((vx0 & vy1) ? 1.f : 0.f);
    const float w3 = aw * fx * fy * ((vx1 & vy1) ? 1.f : 0.f);
    iw_sh[q][r][0] = make_int2(st + y0c * ww + x0c, __float_as_int(w0));
    iw_sh[q][r][1] = make_int2(st + y0c * ww + x1c, __float_as_int(w1));
    iw_sh[q][r][2] = make_int2(st + y1c * ww + x0c, __float_as_int(w2));
    iw_sh[q][r][3] = make_int2(st + y1c * ww + x1c, __float_as_int(w3));
  }
  __syncthreads();

  // gather: q = t>>7, head = (t>>4)&7, dim-pair = t&15
  const int q = t >> 7, h = (t >> 4) & 7, dp = t & 15;
  const unsigned short* vb = v + (size_t)b * LV_ * DM + h * 32 + dp * 2;
  float ax = 0.f, ay = 0.f;
  #pragma unroll
  for (int r = 0; r < 12; ++r) {
    const int rr = h * 12 + r;
    #pragma unroll
    for (int cc = 0; cc < 4; ++cc) {
      const int2 iw = iw_sh[q][rr][cc];
      const float w = __int_as_float(iw.y);
      const unsigned int u = *(const unsigned int*)(vb + (size_t)iw.x * DM);
      ax = fmaf(w, __builtin_bit_cast(float, u << 16), ax);
      ay = fmaf(w, __builtin_bit_cast(float, u & 0xFFFF0000u), ay);
    }
  }
  unsigned short* mp = mid + (size_t)(bq0 + q) * DM + h * 32 + dp * 2;
  *(unsigned int*)mp = pack_bf2(ax, ay);
}

// ---------------------------------------------------------------------------
// Kernel 4: out = mid @ Wout + bout, bf16 MFMA, 64x64 tile, BK=32,
// register-prefetch pipelined (unswapped, col-contiguous stores). grid (75,4).
// ---------------------------------------------------------------------------
__global__ __launch_bounds__(256) void outp_mfma(
    const unsigned short* __restrict__ midb, const unsigned short* __restrict__ WoutT,
    const float* __restrict__ bias, float* __restrict__ out) {
  __shared__ short Ah[4][64][8];   // 4 KB
  __shared__ short Bh[4][64][8];   // 4 KB
  const int tid = threadIdx.x;
  const int lane = tid & 63;
  const int wave = tid >> 6;
  const int l16 = lane & 15, q4 = lane >> 4;
  const int wc = wave * 16;
  const int m0 = blockIdx.x * 64, col0 = blockIdx.y * 64;

  const int r = tid >> 2, ch = tid & 3;   // staging: row, k-chunk
  const unsigned short* apt = midb + (size_t)(m0 + r) * DM + ch * 8;
  const unsigned short* wpt = WoutT + (size_t)(col0 + r) * DM + ch * 8;
  uint4 am = *(const uint4*)apt;
  uint4 wm = *(const uint4*)wpt;

  f32x4 acc[4];
  #pragma unroll
  for (int i = 0; i < 4; ++i) acc[i] = (f32x4)0.f;

  for (int kk = 0; kk < DM; kk += 32) {
    __syncthreads();
    *(uint4*)&Ah[ch][r][0] = am;
    *(uint4*)&Bh[ch][r][0] = wm;
    __syncthreads();
    if (kk + 32 < DM) {
      am = *(const uint4*)(apt + kk + 32);
      wm = *(const uint4*)(wpt + kk + 32);
    }
    const short8 bfrag = *(const short8*)&Bh[q4][wc + l16][0];
    #pragma unroll
    for (int i = 0; i < 4; ++i) {
      const short8 af = *(const short8*)&Ah[q4][i * 16 + l16][0];
      acc[i] = __builtin_amdgcn_mfma_f32_16x16x32_bf16(af, bfrag, acc[i], 0, 0, 0);
    }
  }

  const int col = col0 + wc + l16;
  const float bcol = bias[col];
  #pragma unroll
  for (int i = 0; i < 4; ++i)
    #pragma unroll
    for (int rr = 0; rr < 4; ++rr)
      out[(size_t)(m0 + i * 16 + q4 * 4 + rr) * DM + col] = acc[i][rr] + bcol;
}

extern "C" void kernel_launch(void* const* d_in, const int* in_sizes, int n_in,
                              void* d_out, int out_size, void* d_ws, size_t ws_size,
                              hipStream_t stream) {
  (void)in_sizes; (void)n_in; (void)out_size; (void)ws_size;
  const float* query = (const float*)d_in[0];
  const float* refp  = (const float*)d_in[1];
  const float* value = (const float*)d_in[2];
  const float* Wv    = (const float*)d_in[3];
  const float* bv    = (const float*)d_in[4];
  const float* Woff  = (const float*)d_in[5];
  const float* boff  = (const float*)d_in[6];
  const float* Wattn = (const float*)d_in[7];
  const float* battn = (const float*)d_in[8];
  const float* Wout  = (const float*)d_in[9];
  const float* bout  = (const float*)d_in[10];
  float* out = (float*)d_out;

  char* ws = (char*)d_ws;
  unsigned short* v_bf  = (unsigned short*)ws;              // 68,812,800 B
  unsigned short* WthP  = (unsigned short*)(ws + 68812800); // 131,072 B
  unsigned short* WoutT = (unsigned short*)(ws + 68943872); // 131,072 B
  float* offb   = (float*)(ws + 69074944);                  // 3,686,400 B
  float* logitb = (float*)(ws + 72761344);                  // 1,843,200 B
  unsigned short* midb = (unsigned short*)(ws + 74604544);  // 2,457,600 B

  prep_kernel<<<dim3(8, 8, 2), 256, 0, stream>>>(Wv, Wout, WthP, WoutT);
  gemm_qp<<<dim3(150, 9), 256, 0, stream>>>(query, Woff, boff, Wattn, battn, offb, logitb);
  vproj_mfma<<<2100, 256, 0, stream>>>(value, WthP, bv, v_bf);
  sample_kernel<<<1200, 512, 0, stream>>>(refp, v_bf, offb, logitb, midb);
  outp_mfma<<<dim3(75, 4), 256, 0, stream>>>(midb, WoutT, bout, out);
}

// Round 7
// 291.380 us; speedup vs baseline: 1.0355x; 1.0027x over previous
//
#include <hip/hip_runtime.h>
#include <hip/hip_bf16.h>
#include <cstddef>

#define NB 16
#define NQ 300
#define DM 256
#define LV_ 8400

typedef __attribute__((ext_vector_type(8))) short short8;
typedef __attribute__((ext_vector_type(4))) float f32x4;

static __device__ __forceinline__ unsigned short bf16_rne(float f) {
  unsigned int u = __builtin_bit_cast(unsigned int, f);
  u += 0x7FFFu + ((u >> 16) & 1u);
  return (unsigned short)(u >> 16);
}

static __device__ __forceinline__ unsigned int pack_bf2(float a, float b) {
  __hip_bfloat162 p = __float22bfloat162_rn(make_float2(a, b));
  unsigned int u;
  __builtin_memcpy(&u, &p, 4);
  return u;
}

// async global->LDS, 16 bytes per lane. LDS dest = wave-uniform base + lane*16.
static __device__ __forceinline__ void gload16(const void* g, void* l) {
  __builtin_amdgcn_global_load_lds(
      (const __attribute__((address_space(1))) unsigned int*)g,
      (__attribute__((address_space(3))) unsigned int*)l, 16, 0, 0);
}

// ---------------------------------------------------------------------------
// Kernel 0: weight prep.
//  z==0: Wv -> WthP, bf16, permuted into the exact LDS-staging-linear order
//        [y(col-half)][kb(k/32)][q(k8-chunk)][col(128)][8 bf16]
//        so vproj's B staging is a perfectly-coalesced linear copy.
//  z==1: Wout -> WoutT[n][k] bf16 (plain transpose, as before).
// grid (8,8,2), 256 threads.
// ---------------------------------------------------------------------------
__global__ __launch_bounds__(256) void prep_kernel(
    const float* __restrict__ Wv, const float* __restrict__ Wout,
    unsigned short* __restrict__ WthP, unsigned short* __restrict__ WoutT) {
  __shared__ float tle[32][33];
  const int k0 = blockIdx.x * 32, n0 = blockIdx.y * 32;
  const int xx = threadIdx.x & 31, y4 = (threadIdx.x >> 5) * 4;
  const float* src = blockIdx.z ? Wout : Wv;
  #pragma unroll
  for (int i = 0; i < 4; ++i)
    tle[y4 + i][xx] = src[(size_t)(k0 + y4 + i) * DM + n0 + xx];
  __syncthreads();
  if (blockIdx.z == 0) {
    // WthP[(((y*8 + kb)*4 + q)*128 + col)*8 + f] = bf16(Wv[kb*32+q*8+f][y*128+col])
    if (threadIdx.x < 128) {
      const int nl = threadIdx.x >> 2, q8 = threadIdx.x & 3;
      const int n = n0 + nl, yy = n >> 7, col = n & 127;
      uint4 o;
      o.x = pack_bf2(tle[q8 * 8 + 0][nl], tle[q8 * 8 + 1][nl]);
      o.y = pack_bf2(tle[q8 * 8 + 2][nl], tle[q8 * 8 + 3][nl]);
      o.z = pack_bf2(tle[q8 * 8 + 4][nl], tle[q8 * 8 + 5][nl]);
      o.w = pack_bf2(tle[q8 * 8 + 6][nl], tle[q8 * 8 + 7][nl]);
      const size_t idx = ((((size_t)yy * 8 + blockIdx.x) * 4 + q8) * 128 + col) * 8;
      *(uint4*)&WthP[idx] = o;
    }
  } else {
    #pragma unroll
    for (int i = 0; i < 4; ++i)
      WoutT[(size_t)(n0 + y4 + i) * DM + k0 + xx] = bf16_rne(tle[xx][y4 + i]);
  }
}

// ---------------------------------------------------------------------------
// Kernel 1: v = value @ Wv + bv, bf16 MFMA.
// M=134400, N=K=256. 128x128 tile, BK=32, 4 waves 2x2, 4x4 of 16x16x32.
// v8 = round-6 structure (gload_lds, dbuf, ONE barrier/K-step, XCD swizzle,
// unswapped epilogue) with FULL-ROW A staging: each gload16 covers 8 rows x
// 128 CONTIGUOUS bytes (was 32 rows x 32 B at 1KB stride) -> 4x fewer, 4x
// wider memory requests. LDS layout Af[row][32f] with 16B-unit XOR swizzle
// pu = lu ^ (row&7), applied on BOTH sides (source pre-permuted within the
// row's 128 B; fragment read un-permutes). Bit-identical math.
// ---------------------------------------------------------------------------
__global__ __launch_bounds__(256, 3) void vproj_mfma(
    const float* __restrict__ A, const unsigned short* __restrict__ WthP,
    const float* __restrict__ bias, unsigned short* __restrict__ V) {
  __shared__ float Af[2][128][32];            // 2 x 16 KB, [buf][row][32 fp32]
  __shared__ unsigned short Bf[2][4][128][8]; // 2 x  8 KB, [buf][q][col][8 bf16]
  const int tid = threadIdx.x;
  const int lane = tid & 63;
  const int wave = tid >> 6;
  const int l16 = lane & 15, q4 = lane >> 4;
  const int wr = (wave >> 1) * 64, wc = (wave & 1) * 64;

  // bijective chunked XCD swizzle over 2100 blocks (2100 = 8*262 + 4):
  // work pairs (x,0),(x,1) share the same A stripe -> same-XCD L2 reuse.
  const int b = blockIdx.x;
  const int xcd = b & 7, cidx = b >> 3;
  const int w = (xcd < 4 ? xcd * 263 : 4 * 263 + (xcd - 4) * 262) + cidx;
  const int xb = w >> 1, y = w & 1;
  const size_t row0 = (size_t)xb * 128;
  const int col0 = y * 128;

  const unsigned short* bsrc = WthP + (size_t)y * 8 * 4096;

  // A staging: 4 issues/thread, issue u_ = wave*4+c covers rows u_*8..u_*8+7.
  //   lane: row_ = u_*8 + (lane>>3), physical 16B unit pu = lane&7.
  //   Source holds logical unit lu = pu ^ (row_&7)  (stays inside the SAME
  //   contiguous 128 B row chunk -> 8 rows x 128 B per wave-instruction).
  // B staging: 2 issues/thread, plain linear copy of 1 KB chunks.
#define STAGE(bufi, kb_) do {                                                  \
    _Pragma("unroll")                                                          \
    for (int c_ = 0; c_ < 4; ++c_) {                                           \
      const int u_ = wave * 4 + c_;                                            \
      const int row_ = u_ * 8 + (lane >> 3);                                   \
      const int lu_ = (lane & 7) ^ (row_ & 7);                                 \
      gload16(A + (row0 + row_) * DM + (kb_) * 32 + lu_ * 4,                   \
              (char*)&Af[bufi][0][0] + u_ * 1024);                             \
    }                                                                          \
    _Pragma("unroll")                                                          \
    for (int c_ = 0; c_ < 2; ++c_) {                                           \
      const int u_ = wave * 2 + c_;                                            \
      gload16(bsrc + (size_t)(kb_) * 4096 + u_ * 512 + lane * 8,               \
              (char*)&Bf[bufi][0][0][0] + u_ * 1024);                          \
    }                                                                          \
  } while (0)

  f32x4 acc[4][4];
  #pragma unroll
  for (int i = 0; i < 4; ++i)
    #pragma unroll
    for (int j = 0; j < 4; ++j) acc[i][j] = (f32x4)0.f;

  int buf = 0;
  STAGE(0, 0);
  __syncthreads();

  for (int kb = 0; kb < 8; ++kb) {
    if (kb < 7) STAGE(buf ^ 1, kb + 1);

    short8 bfr[4];
    #pragma unroll
    for (int j = 0; j < 4; ++j)
      bfr[j] = *(const short8*)&Bf[buf][q4][wc + j * 16 + l16][0];

    #pragma unroll
    for (int i = 0; i < 4; ++i) {
      const int r_ = wr + i * 16 + l16;
      const float* rp = &Af[buf][r_][0];
      const int sw = (r_ & 7);
      const float4 lo = *(const float4*)(rp + ((((q4 << 1) + 0) ^ sw) << 2));
      const float4 hi = *(const float4*)(rp + ((((q4 << 1) + 1) ^ sw) << 2));
      uint4 p;
      p.x = pack_bf2(lo.x, lo.y); p.y = pack_bf2(lo.z, lo.w);
      p.z = pack_bf2(hi.x, hi.y); p.w = pack_bf2(hi.z, hi.w);
      const short8 af = __builtin_bit_cast(short8, p);
      #pragma unroll
      for (int j = 0; j < 4; ++j)
        acc[i][j] = __builtin_amdgcn_mfma_f32_16x16x32_bf16(af, bfr[j], acc[i][j], 0, 0, 0);
    }
    __syncthreads();
    buf ^= 1;
  }
#undef STAGE

  // C/D layout: col = lane&15, row = (lane>>4)*4 + r
  #pragma unroll
  for (int i = 0; i < 4; ++i)
    #pragma unroll
    for (int j = 0; j < 4; ++j) {
      const int col = col0 + wc + j * 16 + l16;
      const float bcol = bias[col];
      #pragma unroll
      for (int r = 0; r < 4; ++r) {
        const size_t row = row0 + wr + i * 16 + q4 * 4 + r;
        V[row * DM + col] = bf16_rne(acc[i][j][r] + bcol);
      }
    }
}

// ---------------------------------------------------------------------------
// Kernel 2: fused query projections (offsets N=192 + logits N=96), fp32.
// 32x32 tile, BK=32, 256 threads, 2x2 microtile, register-prefetched.
// grid (150, 9): by<6 -> Woff tile, else -> Wattn tile.
// ---------------------------------------------------------------------------
__global__ __launch_bounds__(256) void gemm_qp(
    const float* __restrict__ q,
    const float* __restrict__ Woff, const float* __restrict__ boff,
    const float* __restrict__ Wattn, const float* __restrict__ battn,
    float* __restrict__ offb, float* __restrict__ logitb) {
  const int by = blockIdx.y;
  const float* W; const float* bias; float* C; int N, c0;
  if (by < 6) { W = Woff;  bias = boff;  C = offb;   N = 192; c0 = by * 32; }
  else        { W = Wattn; bias = battn; C = logitb; N = 96;  c0 = (by - 6) * 32; }
  const int m0 = blockIdx.x * 32;

  __shared__ float As[32][33];   // As[k][m]
  __shared__ float Bs[32][33];   // Bs[k][n]
  const int tid = threadIdx.x;
  const int ar = tid >> 3, ak = (tid & 7) * 4;
  const int kr = tid >> 3, bc = (tid & 7) * 4;
  const int tx = tid & 15, ty = tid >> 4;

  const float* apt = q + (size_t)(m0 + ar) * DM + ak;
  float4 av = *(const float4*)apt;
  float4 wv = *(const float4*)(W + (size_t)kr * N + c0 + bc);

  float acc[2][2] = {{0.f, 0.f}, {0.f, 0.f}};
  for (int kk = 0; kk < DM; kk += 32) {
    __syncthreads();
    As[ak + 0][ar] = av.x;
    As[ak + 1][ar] = av.y;
    As[ak + 2][ar] = av.z;
    As[ak + 3][ar] = av.w;
    *(float4*)&Bs[kr][bc] = wv;
    __syncthreads();
    if (kk + 32 < DM) {
      av = *(const float4*)(apt + kk + 32);
      wv = *(const float4*)(W + (size_t)(kk + 32 + kr) * N + c0 + bc);
    }
    #pragma unroll
    for (int k = 0; k < 32; ++k) {
      const float2 a2 = *(const float2*)&As[k][ty * 2];
      const float2 b2 = *(const float2*)&Bs[k][tx * 2];
      acc[0][0] = fmaf(a2.x, b2.x, acc[0][0]);
      acc[0][1] = fmaf(a2.x, b2.y, acc[0][1]);
      acc[1][0] = fmaf(a2.y, b2.x, acc[1][0]);
      acc[1][1] = fmaf(a2.y, b2.y, acc[1][1]);
    }
  }
  const float b0 = bias[c0 + tx * 2], b1 = bias[c0 + tx * 2 + 1];
  #pragma unroll
  for (int i = 0; i < 2; ++i) {
    float2 o; o.x = acc[i][0] + b0; o.y = acc[i][1] + b1;
    *(float2*)&C[(size_t)(m0 + ty * 2 + i) * N + c0 + tx * 2] = o;
  }
}

// ---------------------------------------------------------------------------
// Kernel 3: softmax + bilinear deformable sampling. 4 queries per block,
// 512 threads, grid 1200. XCD-locality swizzle (each XCD serves 2 batches).
// idx/wt fused into int2 LDS pairs. Writes mid as bf16.
// ---------------------------------------------------------------------------
__global__ __launch_bounds__(512) void sample_kernel(
    const float* __restrict__ refp, const unsigned short* __restrict__ v,
    const float* __restrict__ off, const float* __restrict__ logits,
    unsigned short* __restrict__ mid) {
  // swizzle: XCD = blockIdx%8 (round-robin); give each XCD batches {c, c+8}
  const int x = blockIdx.x;
  const int c8 = x & 7, kb = x >> 3;          // kb in [0,150)
  const int b = c8 + (kb >= 75 ? 8 : 0);
  const int qp = (kb >= 75 ? kb - 75 : kb);
  const int bq0 = b * NQ + qp * 4;
  const int t = threadIdx.x;
  __shared__ float off_sh[4][192];
  __shared__ float aw_sh[4][96];
  __shared__ int2  iw_sh[4][96][4];   // {index, weight-bits}
  __shared__ float ref_sh[4][2];

  {
    const float* osrc = off + (size_t)bq0 * 192;
    float* odst = &off_sh[0][0];
    odst[t] = osrc[t];
    if (t < 256) odst[512 + t] = osrc[512 + t];
    const float* lsrc = logits + (size_t)bq0 * 96;
    if (t < 384) (&aw_sh[0][0])[t] = lsrc[t];
    if (t < 8) ref_sh[t >> 1][t & 1] = refp[(bq0 + (t >> 1)) * 4 + (t & 1)];
  }
  __syncthreads();

  if (t < 32) {
    const int q = t >> 3, h = t & 7;
    float* aw = &aw_sh[q][h * 12];
    float m = -1e30f;
    #pragma unroll
    for (int i = 0; i < 12; ++i) m = fmaxf(m, aw[i]);
    float e[12], s = 0.f;
    #pragma unroll
    for (int i = 0; i < 12; ++i) { e[i] = __expf(aw[i] - m); s += e[i]; }
    const float inv = 1.f / s;
    #pragma unroll
    for (int i = 0; i < 12; ++i) aw[i] = e[i] * inv;
  }
  __syncthreads();

  if (t < 384) {
    const int q = t / 96, r = t - q * 96;
    const int h = r / 12, lp = r - h * 12;
    const int l = lp >> 2, p = lp & 3;
    const int LH[3] = {80, 40, 20};
    const int LS[3] = {0, 6400, 8000};
    const int hh = LH[l], ww = LH[l], st = LS[l];
    const int oi = ((h * 3 + l) * 4 + p) * 2;
    const float aw = aw_sh[q][h * 12 + lp];
    const float sx = fminf(fmaxf(ref_sh[q][0] + off_sh[q][oi], 0.f), 1.f);
    const float sy = fminf(fmaxf(ref_sh[q][1] + off_sh[q][oi + 1], 0.f), 1.f);
    const float px = sx * (float)ww - 0.5f;
    const float py = sy * (float)hh - 0.5f;
    const float x0f = floorf(px), y0f = floorf(py);
    const float fx = px - x0f, fy = py - y0f;
    const int x0 = (int)x0f, y0 = (int)y0f;
    const int x1 = x0 + 1, y1 = y0 + 1;
    const bool vx0 = (x0 >= 0) & (x0 < ww), vx1 = (x1 >= 0) & (x1 < ww);
    const bool vy0 = (y0 >= 0) & (y0 < hh), vy1 = (y1 >= 0) & (y1 < hh);
    const int x0c = min(max(x0, 0), ww - 1), x1c = min(max(x1, 0), ww - 1);
    const int y0c = min(max(y0, 0), hh - 1), y1c = min(max(y1, 0), hh - 1);
    const float w0 = aw * (1.f - fx) * (1.f - fy) * ((vx0 & vy0) ? 1.f : 0.f);
    const float w1 = aw * fx * (1.f - fy) * ((vx1 & vy0) ? 1.f : 0.f);
    const float w2 = aw * (1.f - fx) * fy * ((vx0 & vy1) ? 1.f : 0.f);
    const float w3 = aw * fx * fy * ((vx1 & vy1) ? 1.f : 0.f);
    iw_sh[q][r][0] = make_int2(st + y0c * ww + x0c, __float_as_int(w0));
    iw_sh[q][r][1] = make_int2(st + y0c * ww + x1c, __float_as_int(w1));
    iw_sh[q][r][2] = make_int2(st + y1c * ww + x0c, __float_as_int(w2));
    iw_sh[q][r][3] = make_int2(st + y1c * ww + x1c, __float_as_int(w3));
  }
  __syncthreads();

  // gather: q = t>>7, head = (t>>4)&7, dim-pair = t&15
  const int q = t >> 7, h = (t >> 4) & 7, dp = t & 15;
  const unsigned short* vb = v + (size_t)b * LV_ * DM + h * 32 + dp * 2;
  float ax = 0.f, ay = 0.f;
  #pragma unroll
  for (int r = 0; r < 12; ++r) {
    const int rr = h * 12 + r;
    #pragma unroll
    for (int cc = 0; cc < 4; ++cc) {
      const int2 iw = iw_sh[q][rr][cc];
      const float w = __int_as_float(iw.y);
      const unsigned int u = *(const unsigned int*)(vb + (size_t)iw.x * DM);
      ax = fmaf(w, __builtin_bit_cast(float, u << 16), ax);
      ay = fmaf(w, __builtin_bit_cast(float, u & 0xFFFF0000u), ay);
    }
  }
  unsigned short* mp = mid + (size_t)(bq0 + q) * DM + h * 32 + dp * 2;
  *(unsigned int*)mp = pack_bf2(ax, ay);
}

// ---------------------------------------------------------------------------
// Kernel 4: out = mid @ Wout + bout, bf16 MFMA, 64x64 tile, BK=32,
// register-prefetch pipelined (unswapped, col-contiguous stores). grid (75,4).
// ---------------------------------------------------------------------------
__global__ __launch_bounds__(256) void outp_mfma(
    const unsigned short* __restrict__ midb, const unsigned short* __restrict__ WoutT,
    const float* __restrict__ bias, float* __restrict__ out) {
  __shared__ short Ah[4][64][8];   // 4 KB
  __shared__ short Bh[4][64][8];   // 4 KB
  const int tid = threadIdx.x;
  const int lane = tid & 63;
  const int wave = tid >> 6;
  const int l16 = lane & 15, q4 = lane >> 4;
  const int wc = wave * 16;
  const int m0 = blockIdx.x * 64, col0 = blockIdx.y * 64;

  const int r = tid >> 2, ch = tid & 3;   // staging: row, k-chunk
  const unsigned short* apt = midb + (size_t)(m0 + r) * DM + ch * 8;
  const unsigned short* wpt = WoutT + (size_t)(col0 + r) * DM + ch * 8;
  uint4 am = *(const uint4*)apt;
  uint4 wm = *(const uint4*)wpt;

  f32x4 acc[4];
  #pragma unroll
  for (int i = 0; i < 4; ++i) acc[i] = (f32x4)0.f;

  for (int kk = 0; kk < DM; kk += 32) {
    __syncthreads();
    *(uint4*)&Ah[ch][r][0] = am;
    *(uint4*)&Bh[ch][r][0] = wm;
    __syncthreads();
    if (kk + 32 < DM) {
      am = *(const uint4*)(apt + kk + 32);
      wm = *(const uint4*)(wpt + kk + 32);
    }
    const short8 bfrag = *(const short8*)&Bh[q4][wc + l16][0];
    #pragma unroll
    for (int i = 0; i < 4; ++i) {
      const short8 af = *(const short8*)&Ah[q4][i * 16 + l16][0];
      acc[i] = __builtin_amdgcn_mfma_f32_16x16x32_bf16(af, bfrag, acc[i], 0, 0, 0);
    }
  }

  const int col = col0 + wc + l16;
  const float bcol = bias[col];
  #pragma unroll
  for (int i = 0; i < 4; ++i)
    #pragma unroll
    for (int rr = 0; rr < 4; ++rr)
      out[(size_t)(m0 + i * 16 + q4 * 4 + rr) * DM + col] = acc[i][rr] + bcol;
}

extern "C" void kernel_launch(void* const* d_in, const int* in_sizes, int n_in,
                              void* d_out, int out_size, void* d_ws, size_t ws_size,
                              hipStream_t stream) {
  (void)in_sizes; (void)n_in; (void)out_size; (void)ws_size;
  const float* query = (const float*)d_in[0];
  const float* refp  = (const float*)d_in[1];
  const float* value = (const float*)d_in[2];
  const float* Wv    = (const float*)d_in[3];
  const float* bv    = (const float*)d_in[4];
  const float* Woff  = (const float*)d_in[5];
  const float* boff  = (const float*)d_in[6];
  const float* Wattn = (const float*)d_in[7];
  const float* battn = (const float*)d_in[8];
  const float* Wout  = (const float*)d_in[9];
  const float* bout  = (const float*)d_in[10];
  float* out = (float*)d_out;

  char* ws = (char*)d_ws;
  unsigned short* v_bf  = (unsigned short*)ws;              // 68,812,800 B
  unsigned short* WthP  = (unsigned short*)(ws + 68812800); // 131,072 B
  unsigned short* WoutT = (unsigned short*)(ws + 68943872); // 131,072 B
  float* offb   = (float*)(ws + 69074944);                  // 3,686,400 B
  float* logitb = (float*)(ws + 72761344);                  // 1,843,200 B
  unsigned short* midb = (unsigned short*)(ws + 74604544);  // 2,457,600 B

  prep_kernel<<<dim3(8, 8, 2), 256, 0, stream>>>(Wv, Wout, WthP, WoutT);
  gemm_qp<<<dim3(150, 9), 256, 0, stream>>>(query, Woff, boff, Wattn, battn, offb, logitb);
  vproj_mfma<<<2100, 256, 0, stream>>>(value, WthP, bv, v_bf);
  sample_kernel<<<1200, 512, 0, stream>>>(refp, v_bf, offb, logitb, midb);
  outp_mfma<<<dim3(75, 4), 256, 0, stream>>>(midb, WoutT, bout, out);
}